// Round 1
// baseline (645.546 us; speedup 1.0000x reference)
//
#include <hip/hip_runtime.h>
#include <stdint.h>

typedef uint16_t u16;
typedef __attribute__((ext_vector_type(8))) short short8;
typedef __attribute__((ext_vector_type(4))) float f32x4;

#define MFMA16(a, b, c) __builtin_amdgcn_mfma_f32_16x16x32_bf16((a), (b), (c), 0, 0, 0)

__device__ __forceinline__ u16 f2bf(float f) {
  uint32_t u = __float_as_uint(f);
  u += 0x7fffu + ((u >> 16) & 1u);
  return (u16)(u >> 16);
}

// ---------------- fp32 -> bf16 ----------------
__global__ __launch_bounds__(256) void cvt_bf16(const float* __restrict__ src,
                                                u16* __restrict__ dst, int n4) {
  int i = blockIdx.x * 256 + threadIdx.x;
  if (i >= n4) return;
  float4 v = ((const float4*)src)[i];
  uint2 o;
  o.x = (uint32_t)f2bf(v.x) | ((uint32_t)f2bf(v.y) << 16);
  o.y = (uint32_t)f2bf(v.z) | ((uint32_t)f2bf(v.w) << 16);
  ((uint2*)dst)[i] = o;
}

// ---------------- bf16 GEMM: C[M,N] = A[M,K] * B[N,K]^T ----------------
// OUTF32=0: bf16 out to Cb.  OUTF32=1: f32 + bias out to Cf.
template <int OUTF32>
__global__ __launch_bounds__(256) void gemm_bt(const u16* __restrict__ A,
                                               const u16* __restrict__ B,
                                               u16* __restrict__ Cb,
                                               float* __restrict__ Cf,
                                               const float* __restrict__ bias,
                                               int M, int N, int K) {
  __shared__ u16 As[128 * 32];
  __shared__ u16 Bs[128 * 32];
  const int tid = threadIdx.x;
  const int lane = tid & 63, w = tid >> 6;
  const int wr = w >> 1, wc = w & 1;
  const int lo = lane & 15, q4 = lane >> 4;
  const int m0 = blockIdx.y * 128, n0 = blockIdx.x * 128;
  const f32x4 fzero = {0.f, 0.f, 0.f, 0.f};

  f32x4 acc[4][4];
#pragma unroll
  for (int i = 0; i < 4; ++i)
#pragma unroll
    for (int j = 0; j < 4; ++j) acc[i][j] = fzero;

  for (int k0 = 0; k0 < K; k0 += 32) {
#pragma unroll
    for (int s = 0; s < 2; ++s) {
      const int c = tid + s * 256;
      const int row = c >> 2, cc = c & 3;
      ((uint4*)As)[c] = *((const uint4*)(A + (size_t)(m0 + row) * K + k0) + cc);
      ((uint4*)Bs)[c] = *((const uint4*)(B + (size_t)(n0 + row) * K + k0) + cc);
    }
    __syncthreads();
    short8 af[4], bf[4];
#pragma unroll
    for (int i = 0; i < 4; ++i)
      af[i] = *(const short8*)(As + (wr * 64 + i * 16 + lo) * 32 + q4 * 8);
#pragma unroll
    for (int i = 0; i < 4; ++i)
      bf[i] = *(const short8*)(Bs + (wc * 64 + i * 16 + lo) * 32 + q4 * 8);
#pragma unroll
    for (int i = 0; i < 4; ++i)
#pragma unroll
      for (int j = 0; j < 4; ++j) acc[i][j] = MFMA16(af[i], bf[j], acc[i][j]);
    __syncthreads();
  }

#pragma unroll
  for (int i = 0; i < 4; ++i)
#pragma unroll
    for (int j = 0; j < 4; ++j) {
      const int col = n0 + wc * 64 + j * 16 + lo;
#pragma unroll
      for (int e = 0; e < 4; ++e) {
        const int row = m0 + wr * 64 + i * 16 + q4 * 4 + e;
        const float v = acc[i][j][e];
        if (OUTF32)
          Cf[(size_t)row * N + col] = v + bias[col];
        else
          Cb[(size_t)row * N + col] = f2bf(v);
      }
    }
}

// ---------------- flash attention ----------------
// qkv: [B*T, 3*D] bf16, rows = token, cols: q at h*128, k at 2048+h*128, v at 4096+h*128
// aout: [B*T, D] bf16
__global__ __launch_bounds__(256) void flash_attn(const u16* __restrict__ qkv,
                                                  u16* __restrict__ aout) {
  constexpr int T = 2048, D3 = 6144, HD = 128, D = 2048;
  const int qt = blockIdx.x, h = blockIdx.y, b = blockIdx.z;
  const int tid = threadIdx.x, lane = tid & 63, w = tid >> 6;
  const int lo = lane & 15, q4 = lane >> 4;
  const int q0 = qt * 128;

  const u16* Qb = qkv + (size_t)b * T * D3 + h * HD;
  const u16* Kb = Qb + D;
  const u16* Vb = Qb + 2 * D;

  __shared__ u16 Ks[128 * 136];  // K tile (k-row major, d contiguous); reused as P tile
  __shared__ u16 Vt[128 * 136];  // V transposed: Vt[d][j]

  // Q fragments in registers for the whole block: wave w owns q-rows w*32..w*32+31
  short8 qf[2][4];
#pragma unroll
  for (int i = 0; i < 2; ++i)
#pragma unroll
    for (int kk = 0; kk < 4; ++kk)
      qf[i][kk] = *(const short8*)(Qb + (size_t)(q0 + w * 32 + i * 16 + lo) * D3 +
                                   kk * 32 + q4 * 8);

  const f32x4 fzero = {0.f, 0.f, 0.f, 0.f};
  float m_i[2][4], l_i[2][4];
  f32x4 o[2][8];
#pragma unroll
  for (int i = 0; i < 2; ++i)
#pragma unroll
    for (int e = 0; e < 4; ++e) { m_i[i][e] = -1e30f; l_i[i][e] = 0.f; }
#pragma unroll
  for (int i = 0; i < 2; ++i)
#pragma unroll
    for (int dt = 0; dt < 8; ++dt) o[i][dt] = fzero;

  const float cexp = 0.08838834764831843f * 1.4426950408889634f;  // scale * log2(e)

  for (int kt = 0; kt <= qt; ++kt) {
    const int k0 = kt * 128;
    // ---- stage K and V(transposed) ----
#pragma unroll
    for (int s = 0; s < 8; ++s) {
      const int c = tid + s * 256;
      const int row = c >> 4, cc = c & 15;
      *(uint4*)(&Ks[row * 136 + cc * 8]) =
          *((const uint4*)(Kb + (size_t)(k0 + row) * D3) + cc);
      uint4 vv = *((const uint4*)(Vb + (size_t)(k0 + row) * D3) + cc);
      uint32_t vr[4] = {vv.x, vv.y, vv.z, vv.w};
#pragma unroll
      for (int e = 0; e < 4; ++e) {
        Vt[(cc * 8 + 2 * e) * 136 + row] = (u16)(vr[e] & 0xffffu);
        Vt[(cc * 8 + 2 * e + 1) * 136 + row] = (u16)(vr[e] >> 16);
      }
    }
    __syncthreads();

    // ---- S = Q K^T (per wave: 32 q-rows x 128 k-cols) ----
    f32x4 s8[2][8];
#pragma unroll
    for (int i = 0; i < 2; ++i)
#pragma unroll
      for (int jt = 0; jt < 8; ++jt) s8[i][jt] = fzero;
#pragma unroll
    for (int jt = 0; jt < 8; ++jt)
#pragma unroll
      for (int kk = 0; kk < 4; ++kk) {
        short8 kf = *(const short8*)(&Ks[(jt * 16 + lo) * 136 + kk * 32 + q4 * 8]);
        s8[0][jt] = MFMA16(qf[0][kk], kf, s8[0][jt]);
        s8[1][jt] = MFMA16(qf[1][kk], kf, s8[1][jt]);
      }
    __syncthreads();  // all waves done reading Ks; it becomes the P buffer

    // ---- online softmax (rows owned exclusively per wave) ----
    const bool diag = (kt == qt);
    float alpha[2][4];
#pragma unroll
    for (int i = 0; i < 2; ++i)
#pragma unroll
      for (int e = 0; e < 4; ++e) {
        const int qrow = w * 32 + i * 16 + q4 * 4 + e;  // row within tile
        float sv[8];
        float mx = -1e30f;
#pragma unroll
        for (int jt = 0; jt < 8; ++jt) {
          float v = s8[i][jt][e];
          if (diag && (jt * 16 + lo > qrow)) v = -1e30f;
          sv[jt] = v;
          mx = fmaxf(mx, v);
        }
#pragma unroll
        for (int off = 1; off < 16; off <<= 1) mx = fmaxf(mx, __shfl_xor(mx, off));
        const float mold = m_i[i][e];
        const float mnew = fmaxf(mold, mx);
        const float a = exp2f((mold - mnew) * cexp);
        float ls = 0.f;
#pragma unroll
        for (int jt = 0; jt < 8; ++jt) {
          const float p = exp2f((sv[jt] - mnew) * cexp);
          ls += p;
          Ks[qrow * 136 + jt * 16 + lo] = f2bf(p);  // P write (aliases Ks)
        }
#pragma unroll
        for (int off = 1; off < 16; off <<= 1) ls += __shfl_xor(ls, off);
        m_i[i][e] = mnew;
        l_i[i][e] = l_i[i][e] * a + ls;
        alpha[i][e] = a;
      }
    // rescale O accumulator
#pragma unroll
    for (int i = 0; i < 2; ++i)
#pragma unroll
      for (int dt = 0; dt < 8; ++dt) {
        f32x4 t = o[i][dt];
        t[0] *= alpha[i][0]; t[1] *= alpha[i][1];
        t[2] *= alpha[i][2]; t[3] *= alpha[i][3];
        o[i][dt] = t;
      }
    __syncthreads();  // P fully written

    // ---- O += P V ----
    short8 pa[2][4];
#pragma unroll
    for (int i = 0; i < 2; ++i)
#pragma unroll
      for (int kk = 0; kk < 4; ++kk)
        pa[i][kk] = *(const short8*)(&Ks[(w * 32 + i * 16 + lo) * 136 + kk * 32 + q4 * 8]);
#pragma unroll
    for (int dt = 0; dt < 8; ++dt)
#pragma unroll
      for (int kk = 0; kk < 4; ++kk) {
        short8 vf = *(const short8*)(&Vt[(dt * 16 + lo) * 136 + kk * 32 + q4 * 8]);
        o[0][dt] = MFMA16(pa[0][kk], vf, o[0][dt]);
        o[1][dt] = MFMA16(pa[1][kk], vf, o[1][dt]);
      }
    __syncthreads();  // protect Ks/Vt before next iteration's staging
  }

  // ---- epilogue: O / l, store bf16 ----
#pragma unroll
  for (int i = 0; i < 2; ++i)
#pragma unroll
    for (int e = 0; e < 4; ++e) {
      const float inv = 1.f / l_i[i][e];
      const int row = q0 + w * 32 + i * 16 + q4 * 4 + e;
#pragma unroll
      for (int dt = 0; dt < 8; ++dt)
        aout[(size_t)(b * T + row) * D + h * HD + dt * 16 + lo] =
            f2bf(o[i][dt][e] * inv);
    }
}

extern "C" void kernel_launch(void* const* d_in, const int* in_sizes, int n_in,
                              void* d_out, int out_size, void* d_ws, size_t ws_size,
                              hipStream_t stream) {
  const float* x = (const float*)d_in[0];
  // d_in[1] = causal mask; implemented analytically (exactly equivalent)
  const float* w_qkv = (const float*)d_in[2];
  const float* w_out = (const float*)d_in[3];
  const float* b_out = (const float*)d_in[4];
  float* out = (float*)d_out;

  const int BT = 4096, D = 2048, D3 = 6144;
  u16* xb = (u16*)d_ws;                 // BT*D
  u16* wqkvb = xb + (size_t)BT * D;     // D3*D
  u16* woutb = wqkvb + (size_t)D3 * D;  // D*D
  u16* qkvb = woutb + (size_t)D * D;    // BT*D3
  u16* attnb = qkvb + (size_t)BT * D3;  // BT*D

  cvt_bf16<<<BT * D / 4 / 256, 256, 0, stream>>>(x, xb, BT * D / 4);
  cvt_bf16<<<D3 * D / 4 / 256, 256, 0, stream>>>(w_qkv, wqkvb, D3 * D / 4);
  cvt_bf16<<<D * D / 4 / 256, 256, 0, stream>>>(w_out, woutb, D * D / 4);

  gemm_bt<0><<<dim3(D3 / 128, BT / 128), 256, 0, stream>>>(
      xb, wqkvb, qkvb, nullptr, nullptr, BT, D3, D);
  flash_attn<<<dim3(16, 16, 2), 256, 0, stream>>>(qkvb, attnb);
  gemm_bt<1><<<dim3(D / 128, BT / 128), 256, 0, stream>>>(
      attnb, woutb, nullptr, out, b_out, BT, D, D);
}

// Round 2
// 520.821 us; speedup vs baseline: 1.2395x; 1.2395x over previous
//
#include <hip/hip_runtime.h>
#include <stdint.h>

typedef uint16_t u16;
typedef __attribute__((ext_vector_type(8))) short short8;
typedef __attribute__((ext_vector_type(4))) float f32x4;

#define MFMA16(a, b, c) __builtin_amdgcn_mfma_f32_16x16x32_bf16((a), (b), (c), 0, 0, 0)
#define AS1 __attribute__((address_space(1)))
#define AS3 __attribute__((address_space(3)))

__device__ __forceinline__ void gld_lds16(const u16* g, u16* l) {
  __builtin_amdgcn_global_load_lds((const AS1 void*)g, (AS3 void*)l, 16, 0, 0);
}

__device__ __forceinline__ u16 f2bf(float f) {
  uint32_t u = __float_as_uint(f);
  u += 0x7fffu + ((u >> 16) & 1u);
  return (u16)(u >> 16);
}

// ---------------- fp32 -> bf16 ----------------
__global__ __launch_bounds__(256) void cvt_bf16(const float* __restrict__ src,
                                                u16* __restrict__ dst, int n4) {
  int i = blockIdx.x * 256 + threadIdx.x;
  if (i >= n4) return;
  float4 v = ((const float4*)src)[i];
  uint2 o;
  o.x = (uint32_t)f2bf(v.x) | ((uint32_t)f2bf(v.y) << 16);
  o.y = (uint32_t)f2bf(v.z) | ((uint32_t)f2bf(v.w) << 16);
  ((uint2*)dst)[i] = o;
}

// ---------------- bf16 GEMM: C[M,N] = A[M,K] * B[N,K]^T ----------------
// m97 structure: 128x128 tile, BK=32, global_load_lds width-16 staging.
template <int OUTF32>
__global__ __launch_bounds__(256) void gemm_bt(const u16* __restrict__ A,
                                               const u16* __restrict__ B,
                                               u16* __restrict__ Cb,
                                               float* __restrict__ Cf,
                                               const float* __restrict__ bias,
                                               int M, int N, int K) {
  __shared__ u16 As[128 * 32];
  __shared__ u16 Bs[128 * 32];
  const int tid = threadIdx.x;
  const int lane = tid & 63, w = tid >> 6;
  const int wr = w >> 1, wc = w & 1;
  const int lo = lane & 15, q4 = lane >> 4;
  const int m0 = blockIdx.y * 128, n0 = blockIdx.x * 128;
  const f32x4 fzero = {0.f, 0.f, 0.f, 0.f};

  f32x4 acc[4][4];
#pragma unroll
  for (int i = 0; i < 4; ++i)
#pragma unroll
    for (int j = 0; j < 4; ++j) acc[i][j] = fzero;

  for (int k0 = 0; k0 < K; k0 += 32) {
#pragma unroll
    for (int s = 0; s < 2; ++s) {
      const int c = tid + s * 256;
      const int row = c >> 2, cc = c & 3;
      gld_lds16(A + (size_t)(m0 + row) * K + k0 + cc * 8, As + c * 8);
      gld_lds16(B + (size_t)(n0 + row) * K + k0 + cc * 8, Bs + c * 8);
    }
    __syncthreads();  // drains vmcnt (global_load_lds) + lgkm
    short8 af[4], bf[4];
#pragma unroll
    for (int i = 0; i < 4; ++i)
      af[i] = *(const short8*)(As + (wr * 64 + i * 16 + lo) * 32 + q4 * 8);
#pragma unroll
    for (int i = 0; i < 4; ++i)
      bf[i] = *(const short8*)(Bs + (wc * 64 + i * 16 + lo) * 32 + q4 * 8);
#pragma unroll
    for (int i = 0; i < 4; ++i)
#pragma unroll
      for (int j = 0; j < 4; ++j) acc[i][j] = MFMA16(af[i], bf[j], acc[i][j]);
    __syncthreads();
  }

#pragma unroll
  for (int i = 0; i < 4; ++i)
#pragma unroll
    for (int j = 0; j < 4; ++j) {
      const int col = n0 + wc * 64 + j * 16 + lo;
#pragma unroll
      for (int e = 0; e < 4; ++e) {
        const int row = m0 + wr * 64 + i * 16 + q4 * 4 + e;
        const float v = acc[i][j][e];
        if (OUTF32)
          Cf[(size_t)row * N + col] = v + bias[col];
        else
          Cb[(size_t)row * N + col] = f2bf(v);
      }
    }
}

// ---------------- flash attention ----------------
// qk : [B*T, 4096] bf16 (Q at h*128, K at 2048 + h*128)
// vt : [2048, 4096] bf16, V^T in layout [h][d][b][t] (row e=h*128+d, col b*2048+t)
// aout: [B*T, 2048] bf16
// Block = pair of q-tiles (15-p, p): 17 k-iters every block; 256 blocks = 1/CU.
__device__ __forceinline__ int swz(int r, int c) {
  return r * 128 + (c ^ (((r ^ (r >> 3)) & 7) << 4));
}

__global__ __launch_bounds__(512, 2) void flash_attn(const u16* __restrict__ qk,
                                                     const u16* __restrict__ vt,
                                                     u16* __restrict__ aout) {
  constexpr int T = 2048, WQK = 4096, D = 2048;
  const int p = blockIdx.x, h = blockIdx.y, b = blockIdx.z;
  const int tid = threadIdx.x, lane = tid & 63, w = tid >> 6;
  const int lo = lane & 15, q4 = lane >> 4;

  __shared__ u16 Ks[128 * 128];  // K tile; reused as P tile
  __shared__ u16 Vs[128 * 128];  // V^T tile: rows d, cols j

  const u16* Qb = qk + (size_t)b * T * WQK + h * 128;
  const u16* Kb = Qb + 2048;
  const u16* Vtb = vt + (size_t)h * 128 * 4096 + b * 2048;

  const float cexp = 0.08838834764831843f * 1.4426950408889634f;  // scale*log2e
  const f32x4 fzero = {0.f, 0.f, 0.f, 0.f};

  for (int half = 0; half < 2; ++half) {
    const int qt = half ? p : 15 - p;
    const int q0 = qt * 128;

    short8 qf[4];
#pragma unroll
    for (int kk = 0; kk < 4; ++kk)
      qf[kk] = *(const short8*)(Qb + (size_t)(q0 + w * 16 + lo) * WQK + kk * 32 + q4 * 8);

    f32x4 o[8];
    float m_i[4], l_i[4];
#pragma unroll
    for (int dt = 0; dt < 8; ++dt) o[dt] = fzero;
#pragma unroll
    for (int e = 0; e < 4; ++e) { m_i[e] = -1e30f; l_i[e] = 0.f; }

    // prefetch k-tile 0 into registers
    uint4 kpre[4], vpre[4];
#pragma unroll
    for (int s = 0; s < 4; ++s) {
      const int c = tid + s * 512, r = c >> 4, cc = c & 15;
      kpre[s] = *(const uint4*)(Kb + (size_t)r * WQK + cc * 8);
      vpre[s] = *(const uint4*)(Vtb + (size_t)r * 4096 + cc * 8);
    }

    for (int kt = 0; kt <= qt; ++kt) {
      __syncthreads();  // previous iteration's LDS reads complete
#pragma unroll
      for (int s = 0; s < 4; ++s) {
        const int c = tid + s * 512, r = c >> 4, cc = c & 15;
        *(uint4*)&Ks[swz(r, cc * 8)] = kpre[s];
        *(uint4*)&Vs[swz(r, cc * 8)] = vpre[s];
      }
      if (kt < qt) {
        const int k0n = (kt + 1) * 128;
#pragma unroll
        for (int s = 0; s < 4; ++s) {
          const int c = tid + s * 512, r = c >> 4, cc = c & 15;
          kpre[s] = *(const uint4*)(Kb + (size_t)(k0n + r) * WQK + cc * 8);
          vpre[s] = *(const uint4*)(Vtb + (size_t)r * 4096 + k0n + cc * 8);
        }
      }
      __syncthreads();  // tiles staged

      // ---- S = Q K^T : wave w owns q-rows w*16..w*16+15, all 128 k-cols ----
      f32x4 s8[8];
#pragma unroll
      for (int jt = 0; jt < 8; ++jt) s8[jt] = fzero;
#pragma unroll
      for (int jt = 0; jt < 8; ++jt)
#pragma unroll
        for (int kk = 0; kk < 4; ++kk) {
          short8 kf = *(const short8*)&Ks[swz(jt * 16 + lo, kk * 32 + q4 * 8)];
          s8[jt] = MFMA16(qf[kk], kf, s8[jt]);
        }
      __syncthreads();  // Ks reads done -> becomes P buffer

      // ---- online softmax ----
      const bool diag = (kt == qt);
      float alpha[4];
#pragma unroll
      for (int e = 0; e < 4; ++e) {
        const int qrow = w * 16 + q4 * 4 + e;
        float sv[8], mx = -1e30f;
#pragma unroll
        for (int jt = 0; jt < 8; ++jt) {
          float v = s8[jt][e];
          if (diag && (jt * 16 + lo > qrow)) v = -1e30f;
          sv[jt] = v;
          mx = fmaxf(mx, v);
        }
#pragma unroll
        for (int off = 1; off < 16; off <<= 1) mx = fmaxf(mx, __shfl_xor(mx, off));
        const float mnew = fmaxf(m_i[e], mx);
        const float a = exp2f((m_i[e] - mnew) * cexp);
        float ls = 0.f;
#pragma unroll
        for (int jt = 0; jt < 8; ++jt) {
          const float pv = exp2f((sv[jt] - mnew) * cexp);
          ls += pv;
          Ks[swz(qrow, jt * 16 + lo)] = f2bf(pv);
        }
#pragma unroll
        for (int off = 1; off < 16; off <<= 1) ls += __shfl_xor(ls, off);
        m_i[e] = mnew;
        l_i[e] = l_i[e] * a + ls;
        alpha[e] = a;
      }
#pragma unroll
      for (int dt = 0; dt < 8; ++dt) {
        f32x4 t = o[dt];
        t[0] *= alpha[0]; t[1] *= alpha[1]; t[2] *= alpha[2]; t[3] *= alpha[3];
        o[dt] = t;
      }
      __syncthreads();  // P fully written

      // ---- O += P V : A-frag = P rows of this wave, B-frag = V^T rows (d) ----
#pragma unroll
      for (int kk = 0; kk < 4; ++kk) {
        short8 pa = *(const short8*)&Ks[swz(w * 16 + lo, kk * 32 + q4 * 8)];
#pragma unroll
        for (int dt = 0; dt < 8; ++dt) {
          short8 vf = *(const short8*)&Vs[swz(dt * 16 + lo, kk * 32 + q4 * 8)];
          o[dt] = MFMA16(pa, vf, o[dt]);
        }
      }
    }

    // ---- epilogue ----
#pragma unroll
    for (int e = 0; e < 4; ++e) {
      const float inv = 1.f / l_i[e];
      const int row = q0 + w * 16 + q4 * 4 + e;
#pragma unroll
      for (int dt = 0; dt < 8; ++dt)
        aout[(size_t)(b * T + row) * D + h * 128 + dt * 16 + lo] =
            f2bf(o[dt][e] * inv);
    }
  }
}

extern "C" void kernel_launch(void* const* d_in, const int* in_sizes, int n_in,
                              void* d_out, int out_size, void* d_ws, size_t ws_size,
                              hipStream_t stream) {
  const float* x = (const float*)d_in[0];
  // d_in[1] = causal mask; applied analytically (exactly equivalent)
  const float* w_qkv = (const float*)d_in[2];
  const float* w_out = (const float*)d_in[3];
  const float* b_out = (const float*)d_in[4];
  float* out = (float*)d_out;

  const int BT = 4096, D = 2048, D3 = 6144;
  u16* xb = (u16*)d_ws;                   // BT*D
  u16* wqkvb = xb + (size_t)BT * D;       // D3*D (Q rows 0..2047, K ..4095, V ..6143)
  u16* woutb = wqkvb + (size_t)D3 * D;    // D*D
  u16* qkb = woutb + (size_t)D * D;       // BT*4096 (Q|K)
  u16* vtb = qkb + (size_t)BT * 4096;     // 2048*4096 (V^T as [h][d][b][t])
  u16* attnb = vtb + (size_t)D * BT;      // BT*D

  cvt_bf16<<<BT * D / 4 / 256, 256, 0, stream>>>(x, xb, BT * D / 4);
  cvt_bf16<<<D3 * D / 4 / 256, 256, 0, stream>>>(w_qkv, wqkvb, D3 * D / 4);
  cvt_bf16<<<D * D / 4 / 256, 256, 0, stream>>>(w_out, woutb, D * D / 4);

  // QK-proj: [4096 x 4096 x 2048]
  gemm_bt<0><<<dim3(32, 32), 256, 0, stream>>>(xb, wqkvb, qkb, nullptr, nullptr,
                                               BT, 4096, D);
  // V^T-proj: Wv * X^T -> [2048 x 4096 x 2048], lands as [h][d][b][t]
  gemm_bt<0><<<dim3(32, 16), 256, 0, stream>>>(wqkvb + (size_t)4096 * D, xb, vtb,
                                               nullptr, nullptr, D, BT, D);
  flash_attn<<<dim3(8, 16, 2), 512, 0, stream>>>(qkb, vtb, attnb);
  // out-proj + bias: [4096 x 2048 x 2048]
  gemm_bt<1><<<dim3(16, 32), 256, 0, stream>>>(attnb, woutb, nullptr, out, b_out,
                                               BT, D, D);
}

// Round 3
// 516.521 us; speedup vs baseline: 1.2498x; 1.0083x over previous
//
#include <hip/hip_runtime.h>
#include <stdint.h>

typedef uint16_t u16;
typedef __attribute__((ext_vector_type(8))) short short8;
typedef __attribute__((ext_vector_type(4))) float f32x4;

#define MFMA16(a, b, c) __builtin_amdgcn_mfma_f32_16x16x32_bf16((a), (b), (c), 0, 0, 0)
#define AS1 __attribute__((address_space(1)))
#define AS3 __attribute__((address_space(3)))

__device__ __forceinline__ void gld_lds16(const u16* g, u16* l) {
  __builtin_amdgcn_global_load_lds((const AS1 void*)g, (AS3 void*)l, 16, 0, 0);
}

__device__ __forceinline__ u16 f2bf(float f) {
  uint32_t u = __float_as_uint(f);
  u += 0x7fffu + ((u >> 16) & 1u);
  return (u16)(u >> 16);
}

// ---------------- fp32 -> bf16 ----------------
__global__ __launch_bounds__(256) void cvt_bf16(const float* __restrict__ src,
                                                u16* __restrict__ dst, int n4) {
  int i = blockIdx.x * 256 + threadIdx.x;
  if (i >= n4) return;
  float4 v = ((const float4*)src)[i];
  uint2 o;
  o.x = (uint32_t)f2bf(v.x) | ((uint32_t)f2bf(v.y) << 16);
  o.y = (uint32_t)f2bf(v.z) | ((uint32_t)f2bf(v.w) << 16);
  ((uint2*)dst)[i] = o;
}

// ---------------- bf16 GEMM: C[M,N] = A[M,K] * B[N,K]^T ----------------
// m97 structure: 128x128 tile, BK=32, global_load_lds width-16 staging.
template <int OUTF32>
__global__ __launch_bounds__(256) void gemm_bt(const u16* __restrict__ A,
                                               const u16* __restrict__ B,
                                               u16* __restrict__ Cb,
                                               float* __restrict__ Cf,
                                               const float* __restrict__ bias,
                                               int M, int N, int K) {
  __shared__ u16 As[128 * 32];
  __shared__ u16 Bs[128 * 32];
  const int tid = threadIdx.x;
  const int lane = tid & 63, w = tid >> 6;
  const int wr = w >> 1, wc = w & 1;
  const int lo = lane & 15, q4 = lane >> 4;
  const int m0 = blockIdx.y * 128, n0 = blockIdx.x * 128;
  const f32x4 fzero = {0.f, 0.f, 0.f, 0.f};

  f32x4 acc[4][4];
#pragma unroll
  for (int i = 0; i < 4; ++i)
#pragma unroll
    for (int j = 0; j < 4; ++j) acc[i][j] = fzero;

  for (int k0 = 0; k0 < K; k0 += 32) {
#pragma unroll
    for (int s = 0; s < 2; ++s) {
      const int c = tid + s * 256;
      const int row = c >> 2, cc = c & 3;
      gld_lds16(A + (size_t)(m0 + row) * K + k0 + cc * 8, As + c * 8);
      gld_lds16(B + (size_t)(n0 + row) * K + k0 + cc * 8, Bs + c * 8);
    }
    __syncthreads();  // drains vmcnt (global_load_lds) + lgkm
    short8 af[4], bf[4];
#pragma unroll
    for (int i = 0; i < 4; ++i)
      af[i] = *(const short8*)(As + (wr * 64 + i * 16 + lo) * 32 + q4 * 8);
#pragma unroll
    for (int i = 0; i < 4; ++i)
      bf[i] = *(const short8*)(Bs + (wc * 64 + i * 16 + lo) * 32 + q4 * 8);
#pragma unroll
    for (int i = 0; i < 4; ++i)
#pragma unroll
      for (int j = 0; j < 4; ++j) acc[i][j] = MFMA16(af[i], bf[j], acc[i][j]);
    __syncthreads();
  }

#pragma unroll
  for (int i = 0; i < 4; ++i)
#pragma unroll
    for (int j = 0; j < 4; ++j) {
      const int col = n0 + wc * 64 + j * 16 + lo;
#pragma unroll
      for (int e = 0; e < 4; ++e) {
        const int row = m0 + wr * 64 + i * 16 + q4 * 4 + e;
        const float v = acc[i][j][e];
        if (OUTF32)
          Cf[(size_t)row * N + col] = v + bias[col];
        else
          Cb[(size_t)row * N + col] = f2bf(v);
      }
    }
}

// ---------------- flash attention ----------------
// qk : [B*T, 4096] bf16 (Q at h*128, K at 2048 + h*128)
// vt : [2048, 4096] bf16, V^T in layout [h][d][b][t] (row e=h*128+d, col b*2048+t)
// aout: [B*T, 2048] bf16
// Block = pair of q-tiles (15-p, p): 17 k-iters every block; 256 blocks = 1/CU.
__device__ __forceinline__ int swz(int r, int c) {
  return r * 128 + (c ^ (((r ^ (r >> 3)) & 7) << 4));
}

// (512,1): grid is exactly 1 block/CU; demanding 2-block residency only forced
// a 128-VGPR cap -> ~285 MB/dispatch of scratch spill (R2 WRITE_SIZE=290MB).
__global__ __launch_bounds__(512, 1) void flash_attn(const u16* __restrict__ qk,
                                                     const u16* __restrict__ vt,
                                                     u16* __restrict__ aout) {
  constexpr int T = 2048, WQK = 4096, D = 2048;
  const int p = blockIdx.x, h = blockIdx.y, b = blockIdx.z;
  const int tid = threadIdx.x, lane = tid & 63, w = tid >> 6;
  const int lo = lane & 15, q4 = lane >> 4;

  __shared__ u16 Ks[128 * 128];  // K tile; reused as P tile
  __shared__ u16 Vs[128 * 128];  // V^T tile: rows d, cols j

  const u16* Qb = qk + (size_t)b * T * WQK + h * 128;
  const u16* Kb = Qb + 2048;
  const u16* Vtb = vt + (size_t)h * 128 * 4096 + b * 2048;

  const float cexp = 0.08838834764831843f * 1.4426950408889634f;  // scale*log2e
  const f32x4 fzero = {0.f, 0.f, 0.f, 0.f};

  for (int half = 0; half < 2; ++half) {
    const int qt = half ? p : 15 - p;
    const int q0 = qt * 128;

    short8 qf[4];
#pragma unroll
    for (int kk = 0; kk < 4; ++kk)
      qf[kk] = *(const short8*)(Qb + (size_t)(q0 + w * 16 + lo) * WQK + kk * 32 + q4 * 8);

    f32x4 o[8];
    float m_i[4], l_i[4];
#pragma unroll
    for (int dt = 0; dt < 8; ++dt) o[dt] = fzero;
#pragma unroll
    for (int e = 0; e < 4; ++e) { m_i[e] = -1e30f; l_i[e] = 0.f; }

    // prefetch k-tile 0 into registers
    uint4 kpre[4], vpre[4];
#pragma unroll
    for (int s = 0; s < 4; ++s) {
      const int c = tid + s * 512, r = c >> 4, cc = c & 15;
      kpre[s] = *(const uint4*)(Kb + (size_t)r * WQK + cc * 8);
      vpre[s] = *(const uint4*)(Vtb + (size_t)r * 4096 + cc * 8);
    }

    for (int kt = 0; kt <= qt; ++kt) {
      __syncthreads();  // previous iteration's LDS reads complete
#pragma unroll
      for (int s = 0; s < 4; ++s) {
        const int c = tid + s * 512, r = c >> 4, cc = c & 15;
        *(uint4*)&Ks[swz(r, cc * 8)] = kpre[s];
        *(uint4*)&Vs[swz(r, cc * 8)] = vpre[s];
      }
      if (kt < qt) {
        const int k0n = (kt + 1) * 128;
#pragma unroll
        for (int s = 0; s < 4; ++s) {
          const int c = tid + s * 512, r = c >> 4, cc = c & 15;
          kpre[s] = *(const uint4*)(Kb + (size_t)(k0n + r) * WQK + cc * 8);
          vpre[s] = *(const uint4*)(Vtb + (size_t)r * 4096 + k0n + cc * 8);
        }
      }
      __syncthreads();  // tiles staged

      // ---- S = Q K^T : wave w owns q-rows w*16..w*16+15, all 128 k-cols ----
      f32x4 s8[8];
#pragma unroll
      for (int jt = 0; jt < 8; ++jt) s8[jt] = fzero;
#pragma unroll
      for (int jt = 0; jt < 8; ++jt)
#pragma unroll
        for (int kk = 0; kk < 4; ++kk) {
          short8 kf = *(const short8*)&Ks[swz(jt * 16 + lo, kk * 32 + q4 * 8)];
          s8[jt] = MFMA16(qf[kk], kf, s8[jt]);
        }
      __syncthreads();  // Ks reads done -> becomes P buffer

      // ---- online softmax ----
      const bool diag = (kt == qt);
      float alpha[4];
#pragma unroll
      for (int e = 0; e < 4; ++e) {
        const int qrow = w * 16 + q4 * 4 + e;
        float sv[8], mx = -1e30f;
#pragma unroll
        for (int jt = 0; jt < 8; ++jt) {
          float v = s8[jt][e];
          if (diag && (jt * 16 + lo > qrow)) v = -1e30f;
          sv[jt] = v;
          mx = fmaxf(mx, v);
        }
#pragma unroll
        for (int off = 1; off < 16; off <<= 1) mx = fmaxf(mx, __shfl_xor(mx, off));
        const float mnew = fmaxf(m_i[e], mx);
        const float a = exp2f((m_i[e] - mnew) * cexp);
        float ls = 0.f;
#pragma unroll
        for (int jt = 0; jt < 8; ++jt) {
          const float pv = exp2f((sv[jt] - mnew) * cexp);
          ls += pv;
          Ks[swz(qrow, jt * 16 + lo)] = f2bf(pv);
        }
#pragma unroll
        for (int off = 1; off < 16; off <<= 1) ls += __shfl_xor(ls, off);
        m_i[e] = mnew;
        l_i[e] = l_i[e] * a + ls;
        alpha[e] = a;
      }
#pragma unroll
      for (int dt = 0; dt < 8; ++dt) {
        f32x4 t = o[dt];
        t[0] *= alpha[0]; t[1] *= alpha[1]; t[2] *= alpha[2]; t[3] *= alpha[3];
        o[dt] = t;
      }
      __syncthreads();  // P fully written

      // ---- O += P V : A-frag = P rows of this wave, B-frag = V^T rows (d) ----
#pragma unroll
      for (int kk = 0; kk < 4; ++kk) {
        short8 pa = *(const short8*)&Ks[swz(w * 16 + lo, kk * 32 + q4 * 8)];
#pragma unroll
        for (int dt = 0; dt < 8; ++dt) {
          short8 vf = *(const short8*)&Vs[swz(dt * 16 + lo, kk * 32 + q4 * 8)];
          o[dt] = MFMA16(pa, vf, o[dt]);
        }
      }
    }

    // ---- epilogue ----
#pragma unroll
    for (int e = 0; e < 4; ++e) {
      const float inv = 1.f / l_i[e];
      const int row = q0 + w * 16 + q4 * 4 + e;
#pragma unroll
      for (int dt = 0; dt < 8; ++dt)
        aout[(size_t)(b * T + row) * D + h * 128 + dt * 16 + lo] =
            f2bf(o[dt][e] * inv);
    }
  }
}

extern "C" void kernel_launch(void* const* d_in, const int* in_sizes, int n_in,
                              void* d_out, int out_size, void* d_ws, size_t ws_size,
                              hipStream_t stream) {
  const float* x = (const float*)d_in[0];
  // d_in[1] = causal mask; applied analytically (exactly equivalent)
  const float* w_qkv = (const float*)d_in[2];
  const float* w_out = (const float*)d_in[3];
  const float* b_out = (const float*)d_in[4];
  float* out = (float*)d_out;

  const int BT = 4096, D = 2048, D3 = 6144;
  u16* xb = (u16*)d_ws;                   // BT*D
  u16* wqkvb = xb + (size_t)BT * D;       // D3*D (Q rows 0..2047, K ..4095, V ..6143)
  u16* woutb = wqkvb + (size_t)D3 * D;    // D*D
  u16* qkb = woutb + (size_t)D * D;       // BT*4096 (Q|K)
  u16* vtb = qkb + (size_t)BT * 4096;     // 2048*4096 (V^T as [h][d][b][t])
  u16* attnb = vtb + (size_t)D * BT;      // BT*D

  cvt_bf16<<<BT * D / 4 / 256, 256, 0, stream>>>(x, xb, BT * D / 4);
  cvt_bf16<<<D3 * D / 4 / 256, 256, 0, stream>>>(w_qkv, wqkvb, D3 * D / 4);
  cvt_bf16<<<D * D / 4 / 256, 256, 0, stream>>>(w_out, woutb, D * D / 4);

  // QK-proj: [4096 x 4096 x 2048]
  gemm_bt<0><<<dim3(32, 32), 256, 0, stream>>>(xb, wqkvb, qkb, nullptr, nullptr,
                                               BT, 4096, D);
  // V^T-proj: Wv * X^T -> [2048 x 4096 x 2048], lands as [h][d][b][t]
  gemm_bt<0><<<dim3(32, 16), 256, 0, stream>>>(wqkvb + (size_t)4096 * D, xb, vtb,
                                               nullptr, nullptr, D, BT, D);
  flash_attn<<<dim3(8, 16, 2), 512, 0, stream>>>(qkb, vtb, attnb);
  // out-proj + bias: [4096 x 2048 x 2048]
  gemm_bt<1><<<dim3(16, 32), 256, 0, stream>>>(attnb, woutb, nullptr, out, b_out,
                                               BT, D, D);
}

// Round 4
// 478.033 us; speedup vs baseline: 1.3504x; 1.0805x over previous
//
#include <hip/hip_runtime.h>
#include <stdint.h>

typedef uint16_t u16;
typedef __attribute__((ext_vector_type(8))) short short8;
typedef __attribute__((ext_vector_type(4))) float f32x4;

#define MFMA16(a, b, c) __builtin_amdgcn_mfma_f32_16x16x32_bf16((a), (b), (c), 0, 0, 0)
#define AS1 __attribute__((address_space(1)))
#define AS3 __attribute__((address_space(3)))

__device__ __forceinline__ void gld_lds16(const u16* g, u16* l) {
  __builtin_amdgcn_global_load_lds((const AS1 void*)g, (AS3 void*)l, 16, 0, 0);
}

__device__ __forceinline__ u16 f2bf(float f) {
  uint32_t u = __float_as_uint(f);
  u += 0x7fffu + ((u >> 16) & 1u);
  return (u16)(u >> 16);
}

// ---------------- fp32 -> bf16 ----------------
__global__ __launch_bounds__(256) void cvt_bf16(const float* __restrict__ src,
                                                u16* __restrict__ dst, int n4) {
  int i = blockIdx.x * 256 + threadIdx.x;
  if (i >= n4) return;
  float4 v = ((const float4*)src)[i];
  uint2 o;
  o.x = (uint32_t)f2bf(v.x) | ((uint32_t)f2bf(v.y) << 16);
  o.y = (uint32_t)f2bf(v.z) | ((uint32_t)f2bf(v.w) << 16);
  ((uint2*)dst)[i] = o;
}

// ---------------- bf16 GEMM: C[M,N] = A[M,K] * B[N,K]^T ----------------
// m97 structure: 128x128 tile, BK=32, global_load_lds width-16 staging.
template <int OUTF32>
__global__ __launch_bounds__(256) void gemm_bt(const u16* __restrict__ A,
                                               const u16* __restrict__ B,
                                               u16* __restrict__ Cb,
                                               float* __restrict__ Cf,
                                               const float* __restrict__ bias,
                                               int M, int N, int K) {
  __shared__ u16 As[128 * 32];
  __shared__ u16 Bs[128 * 32];
  const int tid = threadIdx.x;
  const int lane = tid & 63, w = tid >> 6;
  const int wr = w >> 1, wc = w & 1;
  const int lo = lane & 15, q4 = lane >> 4;
  const int m0 = blockIdx.y * 128, n0 = blockIdx.x * 128;
  const f32x4 fzero = {0.f, 0.f, 0.f, 0.f};

  f32x4 acc[4][4];
#pragma unroll
  for (int i = 0; i < 4; ++i)
#pragma unroll
    for (int j = 0; j < 4; ++j) acc[i][j] = fzero;

  for (int k0 = 0; k0 < K; k0 += 32) {
#pragma unroll
    for (int s = 0; s < 2; ++s) {
      const int c = tid + s * 256;
      const int row = c >> 2, cc = c & 3;
      gld_lds16(A + (size_t)(m0 + row) * K + k0 + cc * 8, As + c * 8);
      gld_lds16(B + (size_t)(n0 + row) * K + k0 + cc * 8, Bs + c * 8);
    }
    __syncthreads();  // drains vmcnt (global_load_lds) + lgkm
    short8 af[4], bf[4];
#pragma unroll
    for (int i = 0; i < 4; ++i)
      af[i] = *(const short8*)(As + (wr * 64 + i * 16 + lo) * 32 + q4 * 8);
#pragma unroll
    for (int i = 0; i < 4; ++i)
      bf[i] = *(const short8*)(Bs + (wc * 64 + i * 16 + lo) * 32 + q4 * 8);
#pragma unroll
    for (int i = 0; i < 4; ++i)
#pragma unroll
      for (int j = 0; j < 4; ++j) acc[i][j] = MFMA16(af[i], bf[j], acc[i][j]);
    __syncthreads();
  }

#pragma unroll
  for (int i = 0; i < 4; ++i)
#pragma unroll
    for (int j = 0; j < 4; ++j) {
      const int col = n0 + wc * 64 + j * 16 + lo;
#pragma unroll
      for (int e = 0; e < 4; ++e) {
        const int row = m0 + wr * 64 + i * 16 + q4 * 4 + e;
        const float v = acc[i][j][e];
        if (OUTF32)
          Cf[(size_t)row * N + col] = v + bias[col];
        else
          Cb[(size_t)row * N + col] = f2bf(v);
      }
    }
}

// ---------------- flash attention ----------------
// qk : [B*T, 4096] bf16 (Q at h*128, K at 2048 + h*128)
// vt : [2048, 4096] bf16, V^T in layout [h][d][b][t] (row e=h*128+d, col b*2048+t)
// aout: [B*T, 2048] bf16
// Block = pair of q-tiles (15-p, p): 17 k-iters every block; 256 blocks = 1/CU.
__device__ __forceinline__ int swz(int r, int c) {
  return r * 128 + (c ^ (((r ^ (r >> 3)) & 7) << 4));
}

// waves_per_eu pinned (2,2): grid is 1 block/CU (8 waves = 2/EU). R2/R3 showed
// the backend spills ~285 MB/dispatch to chase 4 waves/EU (VGPR capped 128);
// pinning grants the 256-VGPR budget and forbids that heuristic.
__global__ __attribute__((amdgpu_flat_work_group_size(512, 512),
                          amdgpu_waves_per_eu(2, 2)))
void flash_attn(const u16* __restrict__ qk, const u16* __restrict__ vt,
                u16* __restrict__ aout) {
  constexpr int T = 2048, WQK = 4096, D = 2048;
  const int p = blockIdx.x, h = blockIdx.y, b = blockIdx.z;
  const int tid = threadIdx.x, lane = tid & 63, w = tid >> 6;
  const int lo = lane & 15, q4 = lane >> 4;

  __shared__ u16 Ks[128 * 128];  // K tile; reused as P tile
  __shared__ u16 Vs[128 * 128];  // V^T tile: rows d, cols j

  const u16* Qb = qk + (size_t)b * T * WQK + h * 128;
  const u16* Kb = Qb + 2048;
  const u16* Vtb = vt + (size_t)h * 128 * 4096 + b * 2048;

  const float cexp = 0.08838834764831843f * 1.4426950408889634f;  // scale*log2e
  const f32x4 fzero = {0.f, 0.f, 0.f, 0.f};

  for (int half = 0; half < 2; ++half) {
    const int qt = half ? p : 15 - p;
    const int q0 = qt * 128;

    short8 qf[4];
#pragma unroll
    for (int kk = 0; kk < 4; ++kk)
      qf[kk] = *(const short8*)(Qb + (size_t)(q0 + w * 16 + lo) * WQK + kk * 32 + q4 * 8);

    f32x4 o[8];
    float m_i[4], l_i[4];
#pragma unroll
    for (int dt = 0; dt < 8; ++dt) o[dt] = fzero;
#pragma unroll
    for (int e = 0; e < 4; ++e) { m_i[e] = -1e30f; l_i[e] = 0.f; }

    // prefetch k-tile 0 into registers
    uint4 kpre[4], vpre[4];
#pragma unroll
    for (int s = 0; s < 4; ++s) {
      const int c = tid + s * 512, r = c >> 4, cc = c & 15;
      kpre[s] = *(const uint4*)(Kb + (size_t)r * WQK + cc * 8);
      vpre[s] = *(const uint4*)(Vtb + (size_t)r * 4096 + cc * 8);
    }

    for (int kt = 0; kt <= qt; ++kt) {
      __syncthreads();  // previous iteration's LDS reads complete
#pragma unroll
      for (int s = 0; s < 4; ++s) {
        const int c = tid + s * 512, r = c >> 4, cc = c & 15;
        *(uint4*)&Ks[swz(r, cc * 8)] = kpre[s];
        *(uint4*)&Vs[swz(r, cc * 8)] = vpre[s];
      }
      if (kt < qt) {
        const int k0n = (kt + 1) * 128;
#pragma unroll
        for (int s = 0; s < 4; ++s) {
          const int c = tid + s * 512, r = c >> 4, cc = c & 15;
          kpre[s] = *(const uint4*)(Kb + (size_t)(k0n + r) * WQK + cc * 8);
          vpre[s] = *(const uint4*)(Vtb + (size_t)r * 4096 + k0n + cc * 8);
        }
      }
      __syncthreads();  // tiles staged

      // ---- S = Q K^T : wave w owns q-rows w*16..w*16+15, all 128 k-cols ----
      f32x4 s8[8];
#pragma unroll
      for (int jt = 0; jt < 8; ++jt) s8[jt] = fzero;
#pragma unroll
      for (int jt = 0; jt < 8; ++jt)
#pragma unroll
        for (int kk = 0; kk < 4; ++kk) {
          short8 kf = *(const short8*)&Ks[swz(jt * 16 + lo, kk * 32 + q4 * 8)];
          s8[jt] = MFMA16(qf[kk], kf, s8[jt]);
        }
      __syncthreads();  // Ks reads done -> becomes P buffer

      // ---- online softmax (mask applied in place; no temp copy) ----
      const bool diag = (kt == qt);
      float alpha[4];
#pragma unroll
      for (int e = 0; e < 4; ++e) {
        const int qrow = w * 16 + q4 * 4 + e;
        float mx = -1e30f;
#pragma unroll
        for (int jt = 0; jt < 8; ++jt) {
          float v = s8[jt][e];
          if (diag && (jt * 16 + lo > qrow)) v = -1e30f;
          s8[jt][e] = v;
          mx = fmaxf(mx, v);
        }
#pragma unroll
        for (int off = 1; off < 16; off <<= 1) mx = fmaxf(mx, __shfl_xor(mx, off));
        const float mnew = fmaxf(m_i[e], mx);
        const float a = exp2f((m_i[e] - mnew) * cexp);
        float ls = 0.f;
#pragma unroll
        for (int jt = 0; jt < 8; ++jt) {
          const float pv = exp2f((s8[jt][e] - mnew) * cexp);
          ls += pv;
          Ks[swz(qrow, jt * 16 + lo)] = f2bf(pv);
        }
#pragma unroll
        for (int off = 1; off < 16; off <<= 1) ls += __shfl_xor(ls, off);
        m_i[e] = mnew;
        l_i[e] = l_i[e] * a + ls;
        alpha[e] = a;
      }
#pragma unroll
      for (int dt = 0; dt < 8; ++dt) {
        f32x4 t = o[dt];
        t[0] *= alpha[0]; t[1] *= alpha[1]; t[2] *= alpha[2]; t[3] *= alpha[3];
        o[dt] = t;
      }
      __syncthreads();  // P fully written

      // ---- O += P V : A-frag = P rows of this wave, B-frag = V^T rows (d) ----
#pragma unroll
      for (int kk = 0; kk < 4; ++kk) {
        short8 pa = *(const short8*)&Ks[swz(w * 16 + lo, kk * 32 + q4 * 8)];
#pragma unroll
        for (int dt = 0; dt < 8; ++dt) {
          short8 vf = *(const short8*)&Vs[swz(dt * 16 + lo, kk * 32 + q4 * 8)];
          o[dt] = MFMA16(pa, vf, o[dt]);
        }
      }
    }

    // ---- epilogue ----
#pragma unroll
    for (int e = 0; e < 4; ++e) {
      const float inv = 1.f / l_i[e];
      const int row = q0 + w * 16 + q4 * 4 + e;
#pragma unroll
      for (int dt = 0; dt < 8; ++dt)
        aout[(size_t)(b * T + row) * D + h * 128 + dt * 16 + lo] =
            f2bf(o[dt][e] * inv);
    }
  }
}

extern "C" void kernel_launch(void* const* d_in, const int* in_sizes, int n_in,
                              void* d_out, int out_size, void* d_ws, size_t ws_size,
                              hipStream_t stream) {
  const float* x = (const float*)d_in[0];
  // d_in[1] = causal mask; applied analytically (exactly equivalent)
  const float* w_qkv = (const float*)d_in[2];
  const float* w_out = (const float*)d_in[3];
  const float* b_out = (const float*)d_in[4];
  float* out = (float*)d_out;

  const int BT = 4096, D = 2048, D3 = 6144;
  u16* xb = (u16*)d_ws;                   // BT*D
  u16* wqkvb = xb + (size_t)BT * D;       // D3*D (Q rows 0..2047, K ..4095, V ..6143)
  u16* woutb = wqkvb + (size_t)D3 * D;    // D*D
  u16* qkb = woutb + (size_t)D * D;       // BT*4096 (Q|K)
  u16* vtb = qkb + (size_t)BT * 4096;     // 2048*4096 (V^T as [h][d][b][t])
  u16* attnb = vtb + (size_t)D * BT;      // BT*D

  cvt_bf16<<<BT * D / 4 / 256, 256, 0, stream>>>(x, xb, BT * D / 4);
  cvt_bf16<<<D3 * D / 4 / 256, 256, 0, stream>>>(w_qkv, wqkvb, D3 * D / 4);
  cvt_bf16<<<D * D / 4 / 256, 256, 0, stream>>>(w_out, woutb, D * D / 4);

  // QK-proj: [4096 x 4096 x 2048]
  gemm_bt<0><<<dim3(32, 32), 256, 0, stream>>>(xb, wqkvb, qkb, nullptr, nullptr,
                                               BT, 4096, D);
  // V^T-proj: Wv * X^T -> [2048 x 4096 x 2048], lands as [h][d][b][t]
  gemm_bt<0><<<dim3(32, 16), 256, 0, stream>>>(wqkvb + (size_t)4096 * D, xb, vtb,
                                               nullptr, nullptr, D, BT, D);
  flash_attn<<<dim3(8, 16, 2), 512, 0, stream>>>(qkb, vtb, attnb);
  // out-proj + bias: [4096 x 2048 x 2048]
  gemm_bt<1><<<dim3(16, 32), 256, 0, stream>>>(attnb, woutb, nullptr, out, b_out,
                                               BT, D, D);
}